// Round 8
// baseline (495.304 us; speedup 1.0000x reference)
//
#include <hip/hip_runtime.h>
#include <hip/hip_bf16.h>

#define H2 16
#define HKV 8
#define DHEAD 128
#define HID 1024
#define NQ 2048

typedef unsigned short u16;
typedef __bf16 bf16x8 __attribute__((ext_vector_type(8)));
typedef float f32x4 __attribute__((ext_vector_type(4)));

__device__ __forceinline__ u16 f2bf(float x) {
    unsigned int u = __float_as_uint(x);
    unsigned int r = (u + 0x7fffu + ((u >> 16) & 1u)) >> 16;
    return (u16)r;
}

// pack two fp32 -> (bf16(hi)<<16)|bf16(lo), round-half-up via +0x8000 then v_perm
__device__ __forceinline__ unsigned int pack_bf16(float hi, float lo) {
    unsigned int a = __float_as_uint(hi) + 0x8000u;
    unsigned int b = __float_as_uint(lo) + 0x8000u;
    return __builtin_amdgcn_perm(a, b, 0x07060302u);
}

__device__ __forceinline__ bf16x8 ld_frag(const u16* p) {
    bf16x8 r;
    *reinterpret_cast<uint4*>(&r) = *reinterpret_cast<const uint4*>(p);
    return r;
}

__device__ __forceinline__ void gload_lds16(const u16* g, u16* l) {
    __builtin_amdgcn_global_load_lds((const __attribute__((address_space(1))) void*)g,
                                     (__attribute__((address_space(3))) void*)l, 16, 0, 0);
}

// ---------------- cast x fp32 -> bf16 ----------------
__global__ __launch_bounds__(256) void cast_f32_bf16(const float* __restrict__ in,
                                                     u16* __restrict__ out, int n4) {
    int i = blockIdx.x * 256 + threadIdx.x;
    if (i < n4) {
        float4 v = reinterpret_cast<const float4*>(in)[i];
        ushort4 o;
        o.x = f2bf(v.x); o.y = f2bf(v.y); o.z = f2bf(v.z); o.w = f2bf(v.w);
        reinterpret_cast<ushort4*>(out)[i] = o;
    }
}

// ---------------- transpose-cast W [K][N] fp32 -> [N][K] bf16 ----------------
__global__ __launch_bounds__(256) void transpose_cast(const float* __restrict__ in,
                                                      u16* __restrict__ out, int K, int N) {
    __shared__ u16 t[32][34];
    int k0 = blockIdx.x * 32, n0 = blockIdx.y * 32;
    for (int c = threadIdx.x; c < 1024; c += 256) {
        int k = c >> 5, n = c & 31;
        t[k][n] = f2bf(in[(size_t)(k0 + k) * N + n0 + n]);
    }
    __syncthreads();
    for (int c = threadIdx.x; c < 1024; c += 256) {
        int n = c >> 5, k = c & 31;
        out[(size_t)(n0 + n) * K + k0 + k] = t[k][n];
    }
}

// ---------------- GEMM: C[M,N] fp32 = A[M,K]bf16 @ Bt[N,K]bf16^T ----------------
__global__ __launch_bounds__(256) void gemm_bf16(const u16* __restrict__ A,
                                                 const u16* __restrict__ Bt,
                                                 float* __restrict__ C,
                                                 int M, int N, int K) {
    __shared__ u16 As[128 * 32];
    __shared__ u16 Bs[128 * 32];
    int tid = threadIdx.x;
    int lane = tid & 63, wave = tid >> 6;
    int quad = lane >> 4, l15 = lane & 15;
    int wr = wave >> 1, wc = wave & 1;
    int m0 = blockIdx.y * 128, n0 = blockIdx.x * 128;

    f32x4 zero = {0.f, 0.f, 0.f, 0.f};
    f32x4 acc[4][4];
    for (int i = 0; i < 4; i++)
        for (int j = 0; j < 4; j++) acc[i][j] = zero;

    int r0 = 16 * wave + (lane >> 2);
    int r1 = r0 + 64;
    int ks0 = (lane & 3) ^ ((r0 >> 1) & 3);
    int ks1 = (lane & 3) ^ ((r1 >> 1) & 3);
    const u16* ga0 = A + (size_t)(m0 + r0) * K + ks0 * 8;
    const u16* ga1 = A + (size_t)(m0 + r1) * K + ks1 * 8;
    const u16* gb0 = Bt + (size_t)(n0 + r0) * K + ks0 * 8;
    const u16* gb1 = Bt + (size_t)(n0 + r1) * K + ks1 * 8;
    u16* la0 = &As[wave * 512];
    u16* la1 = &As[(wave + 4) * 512];
    u16* lb0 = &Bs[wave * 512];
    u16* lb1 = &Bs[(wave + 4) * 512];

    int swz = (quad ^ ((l15 >> 1) & 3)) * 8;

    for (int k0 = 0; k0 < K; k0 += 32) {
        __syncthreads();
        gload_lds16(ga0 + k0, la0);
        gload_lds16(ga1 + k0, la1);
        gload_lds16(gb0 + k0, lb0);
        gload_lds16(gb1 + k0, lb1);
        __syncthreads();
        bf16x8 a[4], b[4];
        #pragma unroll
        for (int i = 0; i < 4; i++) a[i] = ld_frag(&As[(64 * wr + 16 * i + l15) * 32 + swz]);
        #pragma unroll
        for (int j = 0; j < 4; j++) b[j] = ld_frag(&Bs[(64 * wc + 16 * j + l15) * 32 + swz]);
        #pragma unroll
        for (int i = 0; i < 4; i++)
            #pragma unroll
            for (int j = 0; j < 4; j++)
                acc[i][j] = __builtin_amdgcn_mfma_f32_16x16x32_bf16(a[i], b[j], acc[i][j], 0, 0, 0);
    }
    for (int i = 0; i < 4; i++) {
        int rowb = m0 + 64 * wr + 16 * i + quad * 4;
        for (int j = 0; j < 4; j++) {
            int col = n0 + 64 * wc + 16 * j + l15;
            for (int r = 0; r < 4; r++)
                C[(size_t)(rowb + r) * N + col] = acc[i][j][r];
        }
    }
}

// ---------------- fused RMSNorm + RoPE, fp32 in (strided) -> bf16 head-major out ----------------
__global__ __launch_bounds__(256) void norm_rope(const float* __restrict__ raw,
                                                 const float* __restrict__ cosp,
                                                 const float* __restrict__ sinp,
                                                 const float* __restrict__ w,
                                                 u16* __restrict__ out,
                                                 int T, int nh, int rowstride, int coloff,
                                                 float outscale) {
    int wave = threadIdx.x >> 6, lane = threadIdx.x & 63;
    int wid = blockIdx.x * 4 + wave;
    int t = wid / nh, h = wid % nh;
    if (t >= T) return;
    const float* r = raw + (size_t)t * rowstride + coloff + h * 128;
    float v1 = r[lane], v2 = r[lane + 64];
    float ss = v1 * v1 + v2 * v2;
    for (int off = 1; off < 64; off <<= 1) ss += __shfl_xor(ss, off);
    float inv = rsqrtf(ss * (1.f / 128.f) + 1e-6f);
    float n1 = v1 * inv * w[lane], n2 = v2 * inv * w[lane + 64];
    float c = cosp[(size_t)t * 64 + lane], s = sinp[(size_t)t * 64 + lane];
    float o1 = (n1 * c - n2 * s) * outscale;
    float o2 = (n1 * s + n2 * c) * outscale;
    u16* op = out + ((size_t)h * T + t) * 128;
    op[lane] = f2bf(o1);
    op[lane + 64] = f2bf(o2);
}

// ---------------- V: qkvraw[T][4096] (cols 3072..4095) fp32 -> [h][d][T] bf16 ----------------
__global__ __launch_bounds__(256) void v_transpose(const float* __restrict__ vraw,
                                                   u16* __restrict__ Vbt, int T) {
    __shared__ u16 tt[128][72];
    int h = blockIdx.y, t0 = blockIdx.x * 64;
    for (int c = threadIdx.x; c < 8192; c += 256) {
        int r = c >> 7, d = c & 127;
        tt[d][r] = f2bf(vraw[(size_t)(t0 + r) * 4096 + 3072 + h * 128 + d]);
    }
    __syncthreads();
    for (int c = threadIdx.x; c < 8192; c += 256) {
        int d = c >> 6, r = c & 63;
        Vbt[((size_t)h * 128 + d) * T + t0 + r] = tt[d][r];
    }
}

// ---------------- causal MFMA flash attention, merged paired passes ----------------
// Block (h, j) owns q-tiles qa=63-j and qb=j. Their s-tile ranges are prefixes
// (0..qa) ⊇ (0..qb), so ONE staging loop serves both: iterate i=0..qa, stage
// tile i once, compute tile-A always, tile-B when i<=qb. Staged tiles/block:
// 65 -> 64-j (avg 48). Dual iterations: one Ks read feeds 2 QK MFMAs, one Vt
// read feeds 2 PV MFMAs, two independent chains interleave in one wave (2x ILP).
// Ps has 2 regions (A/B coexist): LDS 80 KB = exactly 2 blocks/CU, 512 blocks
// fully co-resident. Alpha-rescale skipped when all lanes have alpha==1.0
// (max unchanged) - bit-exact skip.
__global__ __launch_bounds__(256, 2) void flash_attn(const u16* __restrict__ Qb,
                                                     const u16* __restrict__ Kb,
                                                     const u16* __restrict__ Vbt,
                                                     u16* __restrict__ attn, int T) {
    __shared__ u16 Ks[2][64 * 128];
    __shared__ u16 Vt[2][128 * 64];
    __shared__ u16 Ps[2][64 * 64];
    int tid = threadIdx.x;
    int lane = tid & 63, wave = tid >> 6;
    int quad = lane >> 4, l15 = lane & 15;
    int swb8 = (l15 & 7) * 8;  // row-XOR term: (s^x)*8 == s*8 ^ x*8
    int h = blockIdx.y;
    int j = (int)blockIdx.x;   // 0..31
    int kvh = h >> 1;

    int qa = 63 - j, qb = j;
    int nA = qa + 1, nB = qb + 1;
    int q0a = qa * 64, q0b = qb * 64;

    const u16* kbase = Kb + (size_t)kvh * T * 128;
    const u16* vbase = Vbt + (size_t)kvh * 128 * T;

    int krow_ = (lane >> 4);
    int kseg_ = (lane & 15);
    int vrow_ = (lane >> 3);
    int vseg_ = (lane & 7);

    auto stage = [&](int s0, int b) {
        #pragma unroll
        for (int i = 0; i < 4; i++) {
            int ch = wave * 4 + i;
            int r = ch * 4 + krow_;
            int s = kseg_ ^ (r & 7);
            gload_lds16(kbase + (size_t)(s0 + r) * 128 + s * 8, &Ks[b][ch * 512]);
        }
        #pragma unroll
        for (int i = 0; i < 4; i++) {
            int ch = wave * 4 + i;
            int d = ch * 8 + vrow_;
            int s = vseg_ ^ (d & 7);
            gload_lds16(vbase + (size_t)d * T + s0 + s * 8, &Vt[b][ch * 512]);
        }
    };

    bf16x8 onesf;
    #pragma unroll
    for (int i = 0; i < 8; i++) onesf[i] = (__bf16)1.0f;
    f32x4 zero = {0.f, 0.f, 0.f, 0.f};
    const float L2E = 1.44269504f;

    bf16x8 qfA[4], qfB[4];
    {
        const u16* qpA = Qb + ((size_t)h * T + q0a + 16 * wave + l15) * 128 + quad * 8;
        const u16* qpB = Qb + ((size_t)h * T + q0b + 16 * wave + l15) * 128 + quad * 8;
        #pragma unroll
        for (int kk = 0; kk < 4; kk++) { qfA[kk] = ld_frag(qpA + kk * 32); qfB[kk] = ld_frag(qpB + kk * 32); }
    }

    float mA = -3.0e38f, mB = -3.0e38f;   // per-lane: q-row = 16*wave + l15
    f32x4 lsumA = zero, lsumB = zero;     // C-layout rows: q = 16*wave + quad*4 + r
    f32x4 oA[8], oB[8];
    for (int dt = 0; dt < 8; dt++) { oA[dt] = zero; oB[dt] = zero; }

    int qloc = 16 * wave + l15;

    // softmax update: lane-local max over 16 scores + 2-shuffle butterfly; exp2-fma
    auto softmax_upd = [&](f32x4 sc[4], float& mi) -> float {
        float mt = sc[0][0];
        #pragma unroll
        for (int jt = 0; jt < 4; jt++)
            for (int r = 0; r < 4; r++) mt = fmaxf(mt, sc[jt][r]);
        mt = fmaxf(mt, __shfl_xor(mt, 16));
        mt = fmaxf(mt, __shfl_xor(mt, 32));
        float mnew = fmaxf(mi, mt);
        float alpha = __expf(mi - mnew);
        mi = mnew;
        float mls = mnew * L2E;
        #pragma unroll
        for (int jt = 0; jt < 4; jt++)
            for (int r = 0; r < 4; r++)
                sc[jt][r] = exp2f(fmaf(sc[jt][r], L2E, -mls));
        return alpha;
    };
    auto ps_write = [&](u16* P, f32x4 sc[4]) {
        int prow = 16 * wave + l15;
        #pragma unroll
        for (int jt = 0; jt < 4; jt++) {
            int s8 = 2 * jt + (quad >> 1);
            uint2 wv;
            wv.x = pack_bf16(sc[jt][1], sc[jt][0]);
            wv.y = pack_bf16(sc[jt][3], sc[jt][2]);
            *reinterpret_cast<uint2*>(&P[prow * 64 + (s8 ^ (l15 & 7)) * 8 + (quad & 1) * 4]) = wv;
        }
    };
    auto rescale = [&](float alpha, f32x4& lsum, f32x4 o[8]) {
        if (__any(alpha != 1.0f)) {   // skip when max unchanged for all lanes (alpha==1 exact)
            float av[4];
            #pragma unroll
            for (int r = 0; r < 4; r++) av[r] = __shfl(alpha, quad * 4 + r);
            #pragma unroll
            for (int r = 0; r < 4; r++) lsum[r] *= av[r];
            #pragma unroll
            for (int dt = 0; dt < 8; dt++)
                for (int r = 0; r < 4; r++) o[dt][r] *= av[r];
        }
    };

    stage(0, 0);
    __syncthreads();  // vmcnt(0): tile 0 resident

    for (int i = 0; i < nA; ++i) {
        int b = i & 1;
        if (i + 1 < nA) stage((i + 1) * 64, 1 - b);  // async into other buffer
        bool doB = (i < nB);

        f32x4 scA[4], scB[4];
        for (int jt = 0; jt < 4; jt++) { scA[jt] = zero; scB[jt] = zero; }

        if (doB) {
            #pragma unroll
            for (int kk = 0; kk < 4; kk++)
                #pragma unroll
                for (int jt = 0; jt < 4; jt++) {
                    bf16x8 kfrag = ld_frag(&Ks[b][(jt * 16 + l15) * 128 + ((kk * 32 + quad * 8) ^ swb8)]);
                    scA[jt] = __builtin_amdgcn_mfma_f32_16x16x32_bf16(kfrag, qfA[kk], scA[jt], 0, 0, 0);
                    scB[jt] = __builtin_amdgcn_mfma_f32_16x16x32_bf16(kfrag, qfB[kk], scB[jt], 0, 0, 0);
                }
        } else {
            #pragma unroll
            for (int kk = 0; kk < 4; kk++)
                #pragma unroll
                for (int jt = 0; jt < 4; jt++) {
                    bf16x8 kfrag = ld_frag(&Ks[b][(jt * 16 + l15) * 128 + ((kk * 32 + quad * 8) ^ swb8)]);
                    scA[jt] = __builtin_amdgcn_mfma_f32_16x16x32_bf16(kfrag, qfA[kk], scA[jt], 0, 0, 0);
                }
        }

        if (i == nA - 1) {  // A diagonal tile: mask s > q
            #pragma unroll
            for (int jt = 0; jt < 4; jt++)
                for (int r = 0; r < 4; r++)
                    if (jt * 16 + quad * 4 + r > qloc) scA[jt][r] = -1e30f;
        }
        if (doB && i == nB - 1) {  // B diagonal tile
            #pragma unroll
            for (int jt = 0; jt < 4; jt++)
                for (int r = 0; r < 4; r++)
                    if (jt * 16 + quad * 4 + r > qloc) scB[jt][r] = -1e30f;
        }

        float alphaA = softmax_upd(scA, mA);
        ps_write(Ps[0], scA);
        float alphaB = 1.0f;
        if (doB) {             // B softmax VALU overlaps Ps-A ds_write drain
            alphaB = softmax_upd(scB, mB);
            ps_write(Ps[1], scB);
        }

        rescale(alphaA, lsumA, oA);
        if (doB) rescale(alphaB, lsumB, oB);

        asm volatile("s_waitcnt lgkmcnt(0)" ::: "memory");  // wave-private Ps ordering

        if (doB) {
            #pragma unroll
            for (int kk2 = 0; kk2 < 2; kk2++) {
                bf16x8 paA = ld_frag(&Ps[0][(16 * wave + l15) * 64 + (((4 * kk2 + quad) ^ (l15 & 7)) * 8)]);
                bf16x8 paB = ld_frag(&Ps[1][(16 * wave + l15) * 64 + (((4 * kk2 + quad) ^ (l15 & 7)) * 8)]);
                lsumA = __builtin_amdgcn_mfma_f32_16x16x32_bf16(paA, onesf, lsumA, 0, 0, 0);
                lsumB = __builtin_amdgcn_mfma_f32_16x16x32_bf16(paB, onesf, lsumB, 0, 0, 0);
                #pragma unroll
                for (int dt = 0; dt < 8; dt++) {
                    bf16x8 vb = ld_frag(&Vt[b][(dt * 16 + l15) * 64 + ((kk2 * 32 + quad * 8) ^ swb8)]);
                    oA[dt] = __builtin_amdgcn_mfma_f32_16x16x32_bf16(paA, vb, oA[dt], 0, 0, 0);
                    oB[dt] = __builtin_amdgcn_mfma_f32_16x16x32_bf16(paB, vb, oB[dt], 0, 0, 0);
                }
            }
        } else {
            #pragma unroll
            for (int kk2 = 0; kk2 < 2; kk2++) {
                bf16x8 paA = ld_frag(&Ps[0][(16 * wave + l15) * 64 + (((4 * kk2 + quad) ^ (l15 & 7)) * 8)]);
                lsumA = __builtin_amdgcn_mfma_f32_16x16x32_bf16(paA, onesf, lsumA, 0, 0, 0);
                #pragma unroll
                for (int dt = 0; dt < 8; dt++) {
                    bf16x8 vb = ld_frag(&Vt[b][(dt * 16 + l15) * 64 + ((kk2 * 32 + quad * 8) ^ swb8)]);
                    oA[dt] = __builtin_amdgcn_mfma_f32_16x16x32_bf16(paA, vb, oA[dt], 0, 0, 0);
                }
            }
        }
        __syncthreads();  // drains next-tile loads (post-compute) + buffer handoff
    }

    {
        float inv[4];
        for (int r = 0; r < 4; r++) inv[r] = 1.f / lsumA[r];
        for (int dt = 0; dt < 8; dt++)
            for (int r = 0; r < 4; r++) {
                int row = q0a + 16 * wave + quad * 4 + r;
                attn[(size_t)row * NQ + h * DHEAD + dt * 16 + l15] = f2bf(oA[dt][r] * inv[r]);
            }
        for (int r = 0; r < 4; r++) inv[r] = 1.f / lsumB[r];
        for (int dt = 0; dt < 8; dt++)
            for (int r = 0; r < 4; r++) {
                int row = q0b + 16 * wave + quad * 4 + r;
                attn[(size_t)row * NQ + h * DHEAD + dt * 16 + l15] = f2bf(oB[dt][r] * inv[r]);
            }
    }
}

extern "C" void kernel_launch(void* const* d_in, const int* in_sizes, int n_in,
                              void* d_out, int out_size, void* d_ws, size_t ws_size,
                              hipStream_t stream) {
    const float* x    = (const float*)d_in[0];
    const float* cosp = (const float*)d_in[1];
    const float* sinp = (const float*)d_in[2];
    const float* Wq   = (const float*)d_in[3];
    const float* Wk   = (const float*)d_in[4];
    const float* Wv   = (const float*)d_in[5];
    const float* Wo   = (const float*)d_in[6];
    const float* qnw  = (const float*)d_in[7];
    const float* knw  = (const float*)d_in[8];
    float* out = (float*)d_out;
    const int T = in_sizes[1] / 64;  // 4096

    char* ws = (char*)d_ws;
    size_t off = 0;
    auto alloc = [&](size_t bytes) {
        char* p = ws + off;
        off += (bytes + 255) & ~(size_t)255;
        return p;
    };
    u16*   xb     = (u16*)alloc((size_t)T * HID * 2);
    u16*   Wqkvb  = (u16*)alloc((size_t)4096 * HID * 2);  // rows: q 0..2047, k 2048..3071, v 3072..4095
    u16*   Wob    = (u16*)alloc((size_t)HID * NQ * 2);
    float* qkvraw = (float*)alloc((size_t)T * 4096 * 4);
    u16*   Qb     = (u16*)alloc((size_t)H2 * T * DHEAD * 2);
    u16*   Kb     = (u16*)alloc((size_t)HKV * T * DHEAD * 2);
    u16*   Vbt    = (u16*)alloc((size_t)HKV * DHEAD * T * 2);
    u16*   attn   = (u16*)alloc((size_t)T * NQ * 2);

    cast_f32_bf16<<<(T * HID / 4 + 255) / 256, 256, 0, stream>>>(x, xb, T * HID / 4);
    transpose_cast<<<dim3(HID / 32, NQ / 32), 256, 0, stream>>>(Wq, Wqkvb, HID, NQ);
    transpose_cast<<<dim3(HID / 32, HID / 32), 256, 0, stream>>>(Wk, Wqkvb + (size_t)2048 * HID, HID, HID);
    transpose_cast<<<dim3(HID / 32, HID / 32), 256, 0, stream>>>(Wv, Wqkvb + (size_t)3072 * HID, HID, HID);
    transpose_cast<<<dim3(NQ / 32, HID / 32), 256, 0, stream>>>(Wo, Wob, NQ, HID);

    // fused QKV: C[T][4096]
    gemm_bf16<<<dim3(4096 / 128, T / 128), 256, 0, stream>>>(xb, Wqkvb, qkvraw, T, 4096, HID);

    const float scale = 0.08838834764831845f;  // 128^-0.5 folded into Q
    norm_rope<<<T * H2 / 4, 256, 0, stream>>>(qkvraw, cosp, sinp, qnw, Qb, T, H2, 4096, 0, scale);
    norm_rope<<<T * HKV / 4, 256, 0, stream>>>(qkvraw, cosp, sinp, knw, Kb, T, HKV, 4096, 2048, 1.0f);
    v_transpose<<<dim3(T / 64, HKV), 256, 0, stream>>>(qkvraw, Vbt, T);

    flash_attn<<<dim3(32, H2), 256, 0, stream>>>(Qb, Kb, Vbt, attn, T);

    gemm_bf16<<<dim3(HID / 128, T / 128), 256, 0, stream>>>(attn, Wob, out, T, HID, NQ);
}

// Round 9
// 364.947 us; speedup vs baseline: 1.3572x; 1.3572x over previous
//
#include <hip/hip_runtime.h>
#include <hip/hip_bf16.h>

#define H2 16
#define HKV 8
#define DHEAD 128
#define HID 1024
#define NQ 2048

typedef unsigned short u16;
typedef __bf16 bf16x8 __attribute__((ext_vector_type(8)));
typedef float f32x4 __attribute__((ext_vector_type(4)));

__device__ __forceinline__ u16 f2bf(float x) {
    unsigned int u = __float_as_uint(x);
    unsigned int r = (u + 0x7fffu + ((u >> 16) & 1u)) >> 16;
    return (u16)r;
}
__device__ __forceinline__ float bf2f(u16 x) {
    return __uint_as_float(((unsigned int)x) << 16);
}

// pack two fp32 -> (bf16(hi)<<16)|bf16(lo), round-half-up via +0x8000 then v_perm
__device__ __forceinline__ unsigned int pack_bf16(float hi, float lo) {
    unsigned int a = __float_as_uint(hi) + 0x8000u;
    unsigned int b = __float_as_uint(lo) + 0x8000u;
    return __builtin_amdgcn_perm(a, b, 0x07060302u);
}

__device__ __forceinline__ bf16x8 ld_frag(const u16* p) {
    bf16x8 r;
    *reinterpret_cast<uint4*>(&r) = *reinterpret_cast<const uint4*>(p);
    return r;
}

__device__ __forceinline__ void gload_lds16(const u16* g, u16* l) {
    __builtin_amdgcn_global_load_lds((const __attribute__((address_space(1))) void*)g,
                                     (__attribute__((address_space(3))) void*)l, 16, 0, 0);
}

// ---------------- cast x fp32 -> bf16 ----------------
__global__ __launch_bounds__(256) void cast_f32_bf16(const float* __restrict__ in,
                                                     u16* __restrict__ out, int n4) {
    int i = blockIdx.x * 256 + threadIdx.x;
    if (i < n4) {
        float4 v = reinterpret_cast<const float4*>(in)[i];
        ushort4 o;
        o.x = f2bf(v.x); o.y = f2bf(v.y); o.z = f2bf(v.z); o.w = f2bf(v.w);
        reinterpret_cast<ushort4*>(out)[i] = o;
    }
}

// ---------------- transpose-cast W [K][N] fp32 -> [N][K] bf16 ----------------
__global__ __launch_bounds__(256) void transpose_cast(const float* __restrict__ in,
                                                      u16* __restrict__ out, int K, int N) {
    __shared__ u16 t[32][34];
    int k0 = blockIdx.x * 32, n0 = blockIdx.y * 32;
    for (int c = threadIdx.x; c < 1024; c += 256) {
        int k = c >> 5, n = c & 31;
        t[k][n] = f2bf(in[(size_t)(k0 + k) * N + n0 + n]);
    }
    __syncthreads();
    for (int c = threadIdx.x; c < 1024; c += 256) {
        int n = c >> 5, k = c & 31;
        out[(size_t)(n0 + n) * K + k0 + k] = t[k][n];
    }
}

// two same-shape weights (Wk, Wv) in one launch via blockIdx.z
__global__ __launch_bounds__(256) void transpose_cast2(const float* __restrict__ inA,
                                                       const float* __restrict__ inB,
                                                       u16* __restrict__ outA,
                                                       u16* __restrict__ outB, int K, int N) {
    __shared__ u16 t[32][34];
    const float* in = blockIdx.z ? inB : inA;
    u16* out = blockIdx.z ? outB : outA;
    int k0 = blockIdx.x * 32, n0 = blockIdx.y * 32;
    for (int c = threadIdx.x; c < 1024; c += 256) {
        int k = c >> 5, n = c & 31;
        t[k][n] = f2bf(in[(size_t)(k0 + k) * N + n0 + n]);
    }
    __syncthreads();
    for (int c = threadIdx.x; c < 1024; c += 256) {
        int n = c >> 5, k = c & 31;
        out[(size_t)(n0 + n) * K + k0 + k] = t[k][n];
    }
}

// ---------------- GEMM 128x128: C fp32 = A[M,K]bf16 @ Bt[N,K]bf16^T ----------------
__global__ __launch_bounds__(256) void gemm_bf16(const u16* __restrict__ A,
                                                 const u16* __restrict__ Bt,
                                                 float* __restrict__ C,
                                                 int M, int N, int K) {
    __shared__ u16 As[128 * 32];
    __shared__ u16 Bs[128 * 32];
    int tid = threadIdx.x;
    int lane = tid & 63, wave = tid >> 6;
    int quad = lane >> 4, l15 = lane & 15;
    int wr = wave >> 1, wc = wave & 1;
    int m0 = blockIdx.y * 128, n0 = blockIdx.x * 128;

    f32x4 zero = {0.f, 0.f, 0.f, 0.f};
    f32x4 acc[4][4];
    for (int i = 0; i < 4; i++)
        for (int j = 0; j < 4; j++) acc[i][j] = zero;

    int r0 = 16 * wave + (lane >> 2);
    int r1 = r0 + 64;
    int ks0 = (lane & 3) ^ ((r0 >> 1) & 3);
    int ks1 = (lane & 3) ^ ((r1 >> 1) & 3);
    const u16* ga0 = A + (size_t)(m0 + r0) * K + ks0 * 8;
    const u16* ga1 = A + (size_t)(m0 + r1) * K + ks1 * 8;
    const u16* gb0 = Bt + (size_t)(n0 + r0) * K + ks0 * 8;
    const u16* gb1 = Bt + (size_t)(n0 + r1) * K + ks1 * 8;
    u16* la0 = &As[wave * 512];
    u16* la1 = &As[(wave + 4) * 512];
    u16* lb0 = &Bs[wave * 512];
    u16* lb1 = &Bs[(wave + 4) * 512];

    int swz = (quad ^ ((l15 >> 1) & 3)) * 8;

    for (int k0 = 0; k0 < K; k0 += 32) {
        __syncthreads();
        gload_lds16(ga0 + k0, la0);
        gload_lds16(ga1 + k0, la1);
        gload_lds16(gb0 + k0, lb0);
        gload_lds16(gb1 + k0, lb1);
        __syncthreads();
        bf16x8 a[4], b[4];
        #pragma unroll
        for (int i = 0; i < 4; i++) a[i] = ld_frag(&As[(64 * wr + 16 * i + l15) * 32 + swz]);
        #pragma unroll
        for (int j = 0; j < 4; j++) b[j] = ld_frag(&Bs[(64 * wc + 16 * j + l15) * 32 + swz]);
        #pragma unroll
        for (int i = 0; i < 4; i++)
            #pragma unroll
            for (int j = 0; j < 4; j++)
                acc[i][j] = __builtin_amdgcn_mfma_f32_16x16x32_bf16(a[i], b[j], acc[i][j], 0, 0, 0);
    }
    for (int i = 0; i < 4; i++) {
        int rowb = m0 + 64 * wr + 16 * i + quad * 4;
        for (int j = 0; j < 4; j++) {
            int col = n0 + 64 * wc + 16 * j + l15;
            for (int r = 0; r < 4; r++)
                C[(size_t)(rowb + r) * N + col] = acc[i][j][r];
        }
    }
}

// ---------------- GEMM 128x128 with bf16 output (QKV) ----------------
__global__ __launch_bounds__(256) void gemm_bf16_ob(const u16* __restrict__ A,
                                                    const u16* __restrict__ Bt,
                                                    u16* __restrict__ C,
                                                    int M, int N, int K) {
    __shared__ u16 As[128 * 32];
    __shared__ u16 Bs[128 * 32];
    int tid = threadIdx.x;
    int lane = tid & 63, wave = tid >> 6;
    int quad = lane >> 4, l15 = lane & 15;
    int wr = wave >> 1, wc = wave & 1;
    int m0 = blockIdx.y * 128, n0 = blockIdx.x * 128;

    f32x4 zero = {0.f, 0.f, 0.f, 0.f};
    f32x4 acc[4][4];
    for (int i = 0; i < 4; i++)
        for (int j = 0; j < 4; j++) acc[i][j] = zero;

    int r0 = 16 * wave + (lane >> 2);
    int r1 = r0 + 64;
    int ks0 = (lane & 3) ^ ((r0 >> 1) & 3);
    int ks1 = (lane & 3) ^ ((r1 >> 1) & 3);
    const u16* ga0 = A + (size_t)(m0 + r0) * K + ks0 * 8;
    const u16* ga1 = A + (size_t)(m0 + r1) * K + ks1 * 8;
    const u16* gb0 = Bt + (size_t)(n0 + r0) * K + ks0 * 8;
    const u16* gb1 = Bt + (size_t)(n0 + r1) * K + ks1 * 8;
    u16* la0 = &As[wave * 512];
    u16* la1 = &As[(wave + 4) * 512];
    u16* lb0 = &Bs[wave * 512];
    u16* lb1 = &Bs[(wave + 4) * 512];

    int swz = (quad ^ ((l15 >> 1) & 3)) * 8;

    for (int k0 = 0; k0 < K; k0 += 32) {
        __syncthreads();
        gload_lds16(ga0 + k0, la0);
        gload_lds16(ga1 + k0, la1);
        gload_lds16(gb0 + k0, lb0);
        gload_lds16(gb1 + k0, lb1);
        __syncthreads();
        bf16x8 a[4], b[4];
        #pragma unroll
        for (int i = 0; i < 4; i++) a[i] = ld_frag(&As[(64 * wr + 16 * i + l15) * 32 + swz]);
        #pragma unroll
        for (int j = 0; j < 4; j++) b[j] = ld_frag(&Bs[(64 * wc + 16 * j + l15) * 32 + swz]);
        #pragma unroll
        for (int i = 0; i < 4; i++)
            #pragma unroll
            for (int j = 0; j < 4; j++)
                acc[i][j] = __builtin_amdgcn_mfma_f32_16x16x32_bf16(a[i], b[j], acc[i][j], 0, 0, 0);
    }
    for (int i = 0; i < 4; i++) {
        int rowb = m0 + 64 * wr + 16 * i + quad * 4;
        for (int j = 0; j < 4; j++) {
            int col = n0 + 64 * wc + 16 * j + l15;
            for (int r = 0; r < 4; r++)
                C[(size_t)(rowb + r) * N + col] = f2bf(acc[i][j][r]);
        }
    }
}

// ---------------- GEMM 128x64 tile (Wo): grid 512 -> 2+ blocks/CU ----------------
__global__ __launch_bounds__(256) void gemm_bf16_n64(const u16* __restrict__ A,
                                                     const u16* __restrict__ Bt,
                                                     float* __restrict__ C,
                                                     int M, int N, int K) {
    __shared__ u16 As[128 * 32];
    __shared__ u16 Bs[64 * 32];
    int tid = threadIdx.x;
    int lane = tid & 63, wave = tid >> 6;
    int quad = lane >> 4, l15 = lane & 15;
    int m0 = blockIdx.y * 128, n0 = blockIdx.x * 64;

    f32x4 zero = {0.f, 0.f, 0.f, 0.f};
    f32x4 acc[2][4];
    for (int i = 0; i < 2; i++)
        for (int j = 0; j < 4; j++) acc[i][j] = zero;

    // staging: As 8 chunks (wave handles 2w, 2w+1), Bs 4 chunks (wave handles w)
    int ra0 = 32 * wave + (lane >> 2);
    int ra1 = ra0 + 16;
    int rb  = 16 * wave + (lane >> 2);
    int ksa0 = (lane & 3) ^ ((ra0 >> 1) & 3);
    int ksa1 = (lane & 3) ^ ((ra1 >> 1) & 3);
    int ksb  = (lane & 3) ^ ((rb >> 1) & 3);
    const u16* ga0 = A + (size_t)(m0 + ra0) * K + ksa0 * 8;
    const u16* ga1 = A + (size_t)(m0 + ra1) * K + ksa1 * 8;
    const u16* gb  = Bt + (size_t)(n0 + rb) * K + ksb * 8;
    u16* la0 = &As[(2 * wave) * 512];
    u16* la1 = &As[(2 * wave + 1) * 512];
    u16* lb  = &Bs[wave * 512];

    int swz = (quad ^ ((l15 >> 1) & 3)) * 8;

    for (int k0 = 0; k0 < K; k0 += 32) {
        __syncthreads();
        gload_lds16(ga0 + k0, la0);
        gload_lds16(ga1 + k0, la1);
        gload_lds16(gb + k0, lb);
        __syncthreads();
        bf16x8 a[2], b[4];
        #pragma unroll
        for (int i = 0; i < 2; i++) a[i] = ld_frag(&As[(32 * wave + 16 * i + l15) * 32 + swz]);
        #pragma unroll
        for (int j = 0; j < 4; j++) b[j] = ld_frag(&Bs[(16 * j + l15) * 32 + swz]);
        #pragma unroll
        for (int i = 0; i < 2; i++)
            #pragma unroll
            for (int j = 0; j < 4; j++)
                acc[i][j] = __builtin_amdgcn_mfma_f32_16x16x32_bf16(a[i], b[j], acc[i][j], 0, 0, 0);
    }
    for (int i = 0; i < 2; i++) {
        int rowb = m0 + 32 * wave + 16 * i + quad * 4;
        for (int j = 0; j < 4; j++) {
            int col = n0 + 16 * j + l15;
            for (int r = 0; r < 4; r++)
                C[(size_t)(rowb + r) * N + col] = acc[i][j][r];
        }
    }
}

// ---------------- fused RMSNorm + RoPE, bf16 in [T][4096] -> bf16 head-major out ----------------
// unit 0..15: Q head (cols h*128), unit 16..23: K head (cols 2048 + (h-16)*128)
__global__ __launch_bounds__(256) void norm_rope_qk(const u16* __restrict__ qkv,
                                                    const float* __restrict__ cosp,
                                                    const float* __restrict__ sinp,
                                                    const float* __restrict__ qnw,
                                                    const float* __restrict__ knw,
                                                    u16* __restrict__ Qb,
                                                    u16* __restrict__ Kb,
                                                    int T, float qscale) {
    int wave = threadIdx.x >> 6, lane = threadIdx.x & 63;
    int wid = blockIdx.x * 4 + wave;
    int t = wid / 24, unit = wid % 24;
    if (t >= T) return;
    bool isq = unit < 16;
    int coloff = isq ? unit * 128 : 2048 + (unit - 16) * 128;
    const float* w = isq ? qnw : knw;
    float outscale = isq ? qscale : 1.0f;
    u16* out = isq ? (Qb + ((size_t)unit * T + t) * 128)
                   : (Kb + ((size_t)(unit - 16) * T + t) * 128);
    const u16* r = qkv + (size_t)t * 4096 + coloff;
    float v1 = bf2f(r[lane]), v2 = bf2f(r[lane + 64]);
    float ss = v1 * v1 + v2 * v2;
    for (int off = 1; off < 64; off <<= 1) ss += __shfl_xor(ss, off);
    float inv = rsqrtf(ss * (1.f / 128.f) + 1e-6f);
    float n1 = v1 * inv * w[lane], n2 = v2 * inv * w[lane + 64];
    float c = cosp[(size_t)t * 64 + lane], s = sinp[(size_t)t * 64 + lane];
    float o1 = (n1 * c - n2 * s) * outscale;
    float o2 = (n1 * s + n2 * c) * outscale;
    out[lane] = f2bf(o1);
    out[lane + 64] = f2bf(o2);
}

// ---------------- V: qkv[T][4096] (cols 3072..4095) bf16 -> [h][d][T] bf16 ----------------
__global__ __launch_bounds__(256) void v_transpose(const u16* __restrict__ qkv,
                                                   u16* __restrict__ Vbt, int T) {
    __shared__ u16 tt[128][72];
    int h = blockIdx.y, t0 = blockIdx.x * 64;
    for (int c = threadIdx.x; c < 8192; c += 256) {
        int r = c >> 7, d = c & 127;
        tt[d][r] = qkv[(size_t)(t0 + r) * 4096 + 3072 + h * 128 + d];
    }
    __syncthreads();
    for (int c = threadIdx.x; c < 8192; c += 256) {
        int d = c >> 6, r = c & 63;
        Vbt[((size_t)h * 128 + d) * T + t0 + r] = tt[d][r];
    }
}

// ---------------- causal MFMA flash attention, S^T softmax, paired q-tiles (R7) ----------------
__global__ __launch_bounds__(256) void flash_attn(const u16* __restrict__ Qb,
                                                  const u16* __restrict__ Kb,
                                                  const u16* __restrict__ Vbt,
                                                  u16* __restrict__ attn, int T) {
    __shared__ u16 Ks[2][64 * 128];
    __shared__ u16 Vt[2][128 * 64];
    __shared__ u16 Ps[64 * 64];
    int tid = threadIdx.x;
    int lane = tid & 63, wave = tid >> 6;
    int quad = lane >> 4, l15 = lane & 15;
    int swb8 = (l15 & 7) * 8;  // row-XOR term: (s^x)*8 == s*8 ^ x*8
    int h = blockIdx.y;
    int j = (int)blockIdx.x;   // 0..31
    int kvh = h >> 1;

    const u16* kbase = Kb + (size_t)kvh * T * 128;
    const u16* vbase = Vbt + (size_t)kvh * 128 * T;

    int krow_ = (lane >> 4);
    int kseg_ = (lane & 15);
    int vrow_ = (lane >> 3);
    int vseg_ = (lane & 7);

    auto stage = [&](int s0, int b) {
        #pragma unroll
        for (int i = 0; i < 4; i++) {
            int ch = wave * 4 + i;
            int r = ch * 4 + krow_;
            int s = kseg_ ^ (r & 7);
            gload_lds16(kbase + (size_t)(s0 + r) * 128 + s * 8, &Ks[b][ch * 512]);
        }
        #pragma unroll
        for (int i = 0; i < 4; i++) {
            int ch = wave * 4 + i;
            int d = ch * 8 + vrow_;
            int s = vseg_ ^ (d & 7);
            gload_lds16(vbase + (size_t)d * T + s0 + s * 8, &Vt[b][ch * 512]);
        }
    };

    bf16x8 onesf;
    #pragma unroll
    for (int i = 0; i < 8; i++) onesf[i] = (__bf16)1.0f;
    f32x4 zero = {0.f, 0.f, 0.f, 0.f};
    const float L2E = 1.44269504f;

    for (int pass = 0; pass < 2; ++pass) {
        int qt = pass == 0 ? (63 - j) : j;
        int q0 = qt * 64;

        bf16x8 qf[4];
        {
            const u16* qp = Qb + ((size_t)h * T + q0 + 16 * wave + l15) * 128 + quad * 8;
            #pragma unroll
            for (int kk = 0; kk < 4; kk++) qf[kk] = ld_frag(qp + kk * 32);
        }

        float m_i = -3.0e38f;       // per-lane: q-row = 16*wave + l15
        f32x4 lsum = zero;          // C-layout rows: q = 16*wave + quad*4 + r
        f32x4 o[8];
        for (int dt = 0; dt < 8; dt++) o[dt] = zero;

        int ntiles = qt + 1;
        stage(0, 0);
        __syncthreads();  // vmcnt(0): tile 0 resident

        for (int it = 0; it < ntiles; ++it) {
            int b = it & 1;
            if (it + 1 < ntiles) stage((it + 1) * 64, 1 - b);  // async into other buffer
            int s0 = it * 64;

            // S^T: A=K (m->s), B=Q (n->q). scT[jt][r]: s = jt*16+quad*4+r, q = 16*wave+l15
            f32x4 scT[4];
            for (int jt = 0; jt < 4; jt++) scT[jt] = zero;
            #pragma unroll
            for (int kk = 0; kk < 4; kk++)
                #pragma unroll
                for (int jt = 0; jt < 4; jt++) {
                    bf16x8 kfrag = ld_frag(&Ks[b][(jt * 16 + l15) * 128 + ((kk * 32 + quad * 8) ^ swb8)]);
                    scT[jt] = __builtin_amdgcn_mfma_f32_16x16x32_bf16(kfrag, qf[kk], scT[jt], 0, 0, 0);
                }

            if (s0 == q0) {  // diagonal tile: mask s > q
                int qloc = 16 * wave + l15;
                #pragma unroll
                for (int jt = 0; jt < 4; jt++)
                    for (int r = 0; r < 4; r++)
                        if (jt * 16 + quad * 4 + r > qloc) scT[jt][r] = -1e30f;
            }

            // lane-local max over 16 scores (same q), then 2-step quad butterfly
            float mt = scT[0][0];
            #pragma unroll
            for (int jt = 0; jt < 4; jt++)
                for (int r = 0; r < 4; r++) mt = fmaxf(mt, scT[jt][r]);
            mt = fmaxf(mt, __shfl_xor(mt, 16));
            mt = fmaxf(mt, __shfl_xor(mt, 32));
            float mnew = fmaxf(m_i, mt);
            float alpha = __expf(m_i - mnew);
            m_i = mnew;
            float mls = mnew * L2E;

            #pragma unroll
            for (int jt = 0; jt < 4; jt++)
                for (int r = 0; r < 4; r++)
                    scT[jt][r] = exp2f(fmaf(scT[jt][r], L2E, -mls));

            // P^T -> Ps[q][s]: 4 consecutive s per (jt) -> one packed b64 write
            {
                int prow = 16 * wave + l15;
                #pragma unroll
                for (int jt = 0; jt < 4; jt++) {
                    int s8 = 2 * jt + (quad >> 1);
                    uint2 wv;
                    wv.x = pack_bf16(scT[jt][1], scT[jt][0]);
                    wv.y = pack_bf16(scT[jt][3], scT[jt][2]);
                    *reinterpret_cast<uint2*>(&Ps[prow * 64 + (s8 ^ (l15 & 7)) * 8 + (quad & 1) * 4]) = wv;
                }
            }

            // broadcast alpha to o-rescale rows (q = 16*wave + quad*4 + r)
            float av[4];
            #pragma unroll
            for (int r = 0; r < 4; r++) av[r] = __shfl(alpha, quad * 4 + r);
            #pragma unroll
            for (int r = 0; r < 4; r++) lsum[r] *= av[r];
            #pragma unroll
            for (int dt = 0; dt < 8; dt++)
                for (int r = 0; r < 4; r++) o[dt][r] *= av[r];

            asm volatile("s_waitcnt lgkmcnt(0)" ::: "memory");  // wave-private Ps ordering

            #pragma unroll
            for (int kk2 = 0; kk2 < 2; kk2++) {
                bf16x8 pa = ld_frag(&Ps[(16 * wave + l15) * 64 + (((4 * kk2 + quad) ^ (l15 & 7)) * 8)]);
                lsum = __builtin_amdgcn_mfma_f32_16x16x32_bf16(pa, onesf, lsum, 0, 0, 0);
                #pragma unroll
                for (int dt = 0; dt < 8; dt++) {
                    bf16x8 vb = ld_frag(&Vt[b][(dt * 16 + l15) * 64 + ((kk2 * 32 + quad * 8) ^ swb8)]);
                    o[dt] = __builtin_amdgcn_mfma_f32_16x16x32_bf16(pa, vb, o[dt], 0, 0, 0);
                }
            }
            __syncthreads();  // drains next-tile loads (post-compute) + buffer handoff
        }

        float inv[4];
        for (int r = 0; r < 4; r++) inv[r] = 1.f / lsum[r];
        for (int dt = 0; dt < 8; dt++)
            for (int r = 0; r < 4; r++) {
                int row = q0 + 16 * wave + quad * 4 + r;
                attn[(size_t)row * NQ + h * DHEAD + dt * 16 + l15] = f2bf(o[dt][r] * inv[r]);
            }
    }
}

extern "C" void kernel_launch(void* const* d_in, const int* in_sizes, int n_in,
                              void* d_out, int out_size, void* d_ws, size_t ws_size,
                              hipStream_t stream) {
    const float* x    = (const float*)d_in[0];
    const float* cosp = (const float*)d_in[1];
    const float* sinp = (const float*)d_in[2];
    const float* Wq   = (const float*)d_in[3];
    const float* Wk   = (const float*)d_in[4];
    const float* Wv   = (const float*)d_in[5];
    const float* Wo   = (const float*)d_in[6];
    const float* qnw  = (const float*)d_in[7];
    const float* knw  = (const float*)d_in[8];
    float* out = (float*)d_out;
    const int T = in_sizes[1] / 64;  // 4096

    char* ws = (char*)d_ws;
    size_t off = 0;
    auto alloc = [&](size_t bytes) {
        char* p = ws + off;
        off += (bytes + 255) & ~(size_t)255;
        return p;
    };
    u16*   xb     = (u16*)alloc((size_t)T * HID * 2);
    u16*   Wqkvb  = (u16*)alloc((size_t)4096 * HID * 2);  // rows: q 0..2047, k 2048..3071, v 3072..4095
    u16*   Wob    = (u16*)alloc((size_t)HID * NQ * 2);
    u16*   qkvb   = (u16*)alloc((size_t)T * 4096 * 2);    // bf16 intermediate
    u16*   Qb     = (u16*)alloc((size_t)H2 * T * DHEAD * 2);
    u16*   Kb     = (u16*)alloc((size_t)HKV * T * DHEAD * 2);
    u16*   Vbt    = (u16*)alloc((size_t)HKV * DHEAD * T * 2);
    u16*   attn   = (u16*)alloc((size_t)T * NQ * 2);

    cast_f32_bf16<<<(T * HID / 4 + 255) / 256, 256, 0, stream>>>(x, xb, T * HID / 4);
    transpose_cast<<<dim3(HID / 32, NQ / 32), 256, 0, stream>>>(Wq, Wqkvb, HID, NQ);
    transpose_cast2<<<dim3(HID / 32, HID / 32, 2), 256, 0, stream>>>(
        Wk, Wv, Wqkvb + (size_t)2048 * HID, Wqkvb + (size_t)3072 * HID, HID, HID);
    transpose_cast<<<dim3(NQ / 32, HID / 32), 256, 0, stream>>>(Wo, Wob, NQ, HID);

    // fused QKV: C[T][4096] bf16
    gemm_bf16_ob<<<dim3(4096 / 128, T / 128), 256, 0, stream>>>(xb, Wqkvb, qkvb, T, 4096, HID);

    const float scale = 0.08838834764831845f;  // 128^-0.5 folded into Q
    norm_rope_qk<<<T * 24 / 4, 256, 0, stream>>>(qkvb, cosp, sinp, qnw, knw, Qb, Kb, T, scale);
    v_transpose<<<dim3(T / 64, HKV), 256, 0, stream>>>(qkvb, Vbt, T);

    flash_attn<<<dim3(32, H2), 256, 0, stream>>>(Qb, Kb, Vbt, attn, T);

    gemm_bf16_n64<<<dim3(HID / 64, T / 128), 256, 0, stream>>>(attn, Wob, out, T, HID, NQ);
}

// Round 10
// 342.224 us; speedup vs baseline: 1.4473x; 1.0664x over previous
//
#include <hip/hip_runtime.h>
#include <hip/hip_bf16.h>

#define H2 16
#define HKV 8
#define DHEAD 128
#define HID 1024
#define NQ 2048

typedef unsigned short u16;
typedef __bf16 bf16x8 __attribute__((ext_vector_type(8)));
typedef float f32x4 __attribute__((ext_vector_type(4)));

__device__ __forceinline__ u16 f2bf(float x) {
    unsigned int u = __float_as_uint(x);
    unsigned int r = (u + 0x7fffu + ((u >> 16) & 1u)) >> 16;
    return (u16)r;
}
__device__ __forceinline__ float bf2f(u16 x) {
    return __uint_as_float(((unsigned int)x) << 16);
}

// pack two fp32 -> (bf16(hi)<<16)|bf16(lo)
__device__ __forceinline__ unsigned int pack_bf16(float hi, float lo) {
    unsigned int a = __float_as_uint(hi) + 0x8000u;
    unsigned int b = __float_as_uint(lo) + 0x8000u;
    return __builtin_amdgcn_perm(a, b, 0x07060302u);
}

__device__ __forceinline__ bf16x8 ld_frag(const u16* p) {
    bf16x8 r;
    *reinterpret_cast<uint4*>(&r) = *reinterpret_cast<const uint4*>(p);
    return r;
}

__device__ __forceinline__ void gload_lds16(const u16* g, u16* l) {
    __builtin_amdgcn_global_load_lds((const __attribute__((address_space(1))) void*)g,
                                     (__attribute__((address_space(3))) void*)l, 16, 0, 0);
}

// ---------------- cast x fp32 -> bf16 ----------------
__global__ __launch_bounds__(256) void cast_f32_bf16(const float* __restrict__ in,
                                                     u16* __restrict__ out, int n4) {
    int i = blockIdx.x * 256 + threadIdx.x;
    if (i < n4) {
        float4 v = reinterpret_cast<const float4*>(in)[i];
        ushort4 o;
        o.x = f2bf(v.x); o.y = f2bf(v.y); o.z = f2bf(v.z); o.w = f2bf(v.w);
        reinterpret_cast<ushort4*>(out)[i] = o;
    }
}

// ---------------- all 4 weight transposes in ONE launch ----------------
// Wq[1024,2048]->rows 0..2047 of Wqkvb; Wk->rows 2048..3071; Wv->rows 3072..4095; Wo[2048,1024]->Wob
__global__ __launch_bounds__(256) void transpose_cast_all(const float* __restrict__ Wq,
                                                          const float* __restrict__ Wk,
                                                          const float* __restrict__ Wv,
                                                          const float* __restrict__ Wo,
                                                          u16* __restrict__ Wqkvb,
                                                          u16* __restrict__ Wob) {
    __shared__ u16 t[32][34];
    int bid = blockIdx.x;
    const float* in; u16* out; int K, N, k0, n0;
    if (bid < 2048) {
        in = Wq; out = Wqkvb; K = 1024; N = 2048;
        k0 = (bid & 31) * 32; n0 = (bid >> 5) * 32;
    } else if (bid < 3072) {
        int b = bid - 2048;
        in = Wk; out = Wqkvb + (size_t)2048 * 1024; K = 1024; N = 1024;
        k0 = (b & 31) * 32; n0 = (b >> 5) * 32;
    } else if (bid < 4096) {
        int b = bid - 3072;
        in = Wv; out = Wqkvb + (size_t)3072 * 1024; K = 1024; N = 1024;
        k0 = (b & 31) * 32; n0 = (b >> 5) * 32;
    } else {
        int b = bid - 4096;
        in = Wo; out = Wob; K = 2048; N = 1024;
        k0 = (b & 63) * 32; n0 = (b >> 6) * 32;
    }
    for (int c = threadIdx.x; c < 1024; c += 256) {
        int k = c >> 5, n = c & 31;
        t[k][n] = f2bf(in[(size_t)(k0 + k) * N + n0 + n]);
    }
    __syncthreads();
    for (int c = threadIdx.x; c < 1024; c += 256) {
        int n = c >> 5, k = c & 31;
        out[(size_t)(n0 + n) * K + k0 + k] = t[k][n];
    }
}

// ---------------- GEMM 128x128, BK=64 (two BK=32 slabs): halved barriers ----------------
template <bool OUT_BF16>
__global__ __launch_bounds__(256) void gemm_bf16_t(const u16* __restrict__ A,
                                                   const u16* __restrict__ Bt,
                                                   void* __restrict__ Cv,
                                                   int M, int N, int K) {
    __shared__ u16 As[2][128 * 32];
    __shared__ u16 Bs[2][128 * 32];
    int tid = threadIdx.x;
    int lane = tid & 63, wave = tid >> 6;
    int quad = lane >> 4, l15 = lane & 15;
    int wr = wave >> 1, wc = wave & 1;
    int m0 = blockIdx.y * 128, n0 = blockIdx.x * 128;

    f32x4 zero = {0.f, 0.f, 0.f, 0.f};
    f32x4 acc[4][4];
    for (int i = 0; i < 4; i++)
        for (int j = 0; j < 4; j++) acc[i][j] = zero;

    int r0 = 16 * wave + (lane >> 2);
    int r1 = r0 + 64;
    int ks0 = (lane & 3) ^ ((r0 >> 1) & 3);
    int ks1 = (lane & 3) ^ ((r1 >> 1) & 3);
    const u16* ga0 = A + (size_t)(m0 + r0) * K + ks0 * 8;
    const u16* ga1 = A + (size_t)(m0 + r1) * K + ks1 * 8;
    const u16* gb0 = Bt + (size_t)(n0 + r0) * K + ks0 * 8;
    const u16* gb1 = Bt + (size_t)(n0 + r1) * K + ks1 * 8;

    int swz = (quad ^ ((l15 >> 1) & 3)) * 8;

    for (int k0 = 0; k0 < K; k0 += 64) {
        __syncthreads();
        #pragma unroll
        for (int s = 0; s < 2; s++) {
            gload_lds16(ga0 + k0 + s * 32, &As[s][wave * 512]);
            gload_lds16(ga1 + k0 + s * 32, &As[s][(wave + 4) * 512]);
            gload_lds16(gb0 + k0 + s * 32, &Bs[s][wave * 512]);
            gload_lds16(gb1 + k0 + s * 32, &Bs[s][(wave + 4) * 512]);
        }
        __syncthreads();
        #pragma unroll
        for (int s = 0; s < 2; s++) {
            bf16x8 a[4], b[4];
            #pragma unroll
            for (int i = 0; i < 4; i++) a[i] = ld_frag(&As[s][(64 * wr + 16 * i + l15) * 32 + swz]);
            #pragma unroll
            for (int j = 0; j < 4; j++) b[j] = ld_frag(&Bs[s][(64 * wc + 16 * j + l15) * 32 + swz]);
            #pragma unroll
            for (int i = 0; i < 4; i++)
                #pragma unroll
                for (int j = 0; j < 4; j++)
                    acc[i][j] = __builtin_amdgcn_mfma_f32_16x16x32_bf16(a[i], b[j], acc[i][j], 0, 0, 0);
        }
    }
    for (int i = 0; i < 4; i++) {
        int rowb = m0 + 64 * wr + 16 * i + quad * 4;
        for (int j = 0; j < 4; j++) {
            int col = n0 + 64 * wc + 16 * j + l15;
            for (int r = 0; r < 4; r++) {
                if (OUT_BF16)
                    ((u16*)Cv)[(size_t)(rowb + r) * N + col] = f2bf(acc[i][j][r]);
                else
                    ((float*)Cv)[(size_t)(rowb + r) * N + col] = acc[i][j][r];
            }
        }
    }
}

// ---------------- GEMM 128x64, BK=64 (Wo): 512 blocks, 24KB LDS ----------------
__global__ __launch_bounds__(256) void gemm_bf16_n64(const u16* __restrict__ A,
                                                     const u16* __restrict__ Bt,
                                                     float* __restrict__ C,
                                                     int M, int N, int K) {
    __shared__ u16 As[2][128 * 32];
    __shared__ u16 Bs[2][64 * 32];
    int tid = threadIdx.x;
    int lane = tid & 63, wave = tid >> 6;
    int quad = lane >> 4, l15 = lane & 15;
    int m0 = blockIdx.y * 128, n0 = blockIdx.x * 64;

    f32x4 zero = {0.f, 0.f, 0.f, 0.f};
    f32x4 acc[2][4];
    for (int i = 0; i < 2; i++)
        for (int j = 0; j < 4; j++) acc[i][j] = zero;

    int ra0 = 32 * wave + (lane >> 2);
    int ra1 = ra0 + 16;
    int rb  = 16 * wave + (lane >> 2);
    int ksa0 = (lane & 3) ^ ((ra0 >> 1) & 3);
    int ksa1 = (lane & 3) ^ ((ra1 >> 1) & 3);
    int ksb  = (lane & 3) ^ ((rb >> 1) & 3);
    const u16* ga0 = A + (size_t)(m0 + ra0) * K + ksa0 * 8;
    const u16* ga1 = A + (size_t)(m0 + ra1) * K + ksa1 * 8;
    const u16* gb  = Bt + (size_t)(n0 + rb) * K + ksb * 8;

    int swz = (quad ^ ((l15 >> 1) & 3)) * 8;

    for (int k0 = 0; k0 < K; k0 += 64) {
        __syncthreads();
        #pragma unroll
        for (int s = 0; s < 2; s++) {
            gload_lds16(ga0 + k0 + s * 32, &As[s][(2 * wave) * 512]);
            gload_lds16(ga1 + k0 + s * 32, &As[s][(2 * wave + 1) * 512]);
            gload_lds16(gb + k0 + s * 32, &Bs[s][wave * 512]);
        }
        __syncthreads();
        #pragma unroll
        for (int s = 0; s < 2; s++) {
            bf16x8 a[2], b[4];
            #pragma unroll
            for (int i = 0; i < 2; i++) a[i] = ld_frag(&As[s][(32 * wave + 16 * i + l15) * 32 + swz]);
            #pragma unroll
            for (int j = 0; j < 4; j++) b[j] = ld_frag(&Bs[s][(16 * j + l15) * 32 + swz]);
            #pragma unroll
            for (int i = 0; i < 2; i++)
                #pragma unroll
                for (int j = 0; j < 4; j++)
                    acc[i][j] = __builtin_amdgcn_mfma_f32_16x16x32_bf16(a[i], b[j], acc[i][j], 0, 0, 0);
        }
    }
    for (int i = 0; i < 2; i++) {
        int rowb = m0 + 32 * wave + 16 * i + quad * 4;
        for (int j = 0; j < 4; j++) {
            int col = n0 + 16 * j + l15;
            for (int r = 0; r < 4; r++)
                C[(size_t)(rowb + r) * N + col] = acc[i][j][r];
        }
    }
}

// ---------------- fused RMSNorm + RoPE, bf16 in [T][4096] -> bf16 head-major out ----------------
__global__ __launch_bounds__(256) void norm_rope_qk(const u16* __restrict__ qkv,
                                                    const float* __restrict__ cosp,
                                                    const float* __restrict__ sinp,
                                                    const float* __restrict__ qnw,
                                                    const float* __restrict__ knw,
                                                    u16* __restrict__ Qb,
                                                    u16* __restrict__ Kb,
                                                    int T, float qscale) {
    int wave = threadIdx.x >> 6, lane = threadIdx.x & 63;
    int wid = blockIdx.x * 4 + wave;
    int t = wid / 24, unit = wid % 24;
    if (t >= T) return;
    bool isq = unit < 16;
    int coloff = isq ? unit * 128 : 2048 + (unit - 16) * 128;
    const float* w = isq ? qnw : knw;
    float outscale = isq ? qscale : 1.0f;
    u16* out = isq ? (Qb + ((size_t)unit * T + t) * 128)
                   : (Kb + ((size_t)(unit - 16) * T + t) * 128);
    const u16* r = qkv + (size_t)t * 4096 + coloff;
    float v1 = bf2f(r[lane]), v2 = bf2f(r[lane + 64]);
    float ss = v1 * v1 + v2 * v2;
    for (int off = 1; off < 64; off <<= 1) ss += __shfl_xor(ss, off);
    float inv = rsqrtf(ss * (1.f / 128.f) + 1e-6f);
    float n1 = v1 * inv * w[lane], n2 = v2 * inv * w[lane + 64];
    float c = cosp[(size_t)t * 64 + lane], s = sinp[(size_t)t * 64 + lane];
    float o1 = (n1 * c - n2 * s) * outscale;
    float o2 = (n1 * s + n2 * c) * outscale;
    out[lane] = f2bf(o1);
    out[lane + 64] = f2bf(o2);
}

// ---------------- V: qkv[T][4096] (cols 3072..4095) bf16 -> [h][d][T] bf16 ----------------
__global__ __launch_bounds__(256) void v_transpose(const u16* __restrict__ qkv,
                                                   u16* __restrict__ Vbt, int T) {
    __shared__ u16 tt[128][72];
    int h = blockIdx.y, t0 = blockIdx.x * 64;
    for (int c = threadIdx.x; c < 8192; c += 256) {
        int r = c >> 7, d = c & 127;
        tt[d][r] = qkv[(size_t)(t0 + r) * 4096 + 3072 + h * 128 + d];
    }
    __syncthreads();
    for (int c = threadIdx.x; c < 8192; c += 256) {
        int d = c >> 6, r = c & 63;
        Vbt[((size_t)h * 128 + d) * T + t0 + r] = tt[d][r];
    }
}

// ---------------- causal MFMA flash attention, S^T softmax, paired q-tiles ----------------
// R7 structure + alpha-skip: rescale block skipped (wave-uniform branch) when all
// lanes' alpha == 1.0 exactly (running max unchanged) — bit-exact.
__global__ __launch_bounds__(256) void flash_attn(const u16* __restrict__ Qb,
                                                  const u16* __restrict__ Kb,
                                                  const u16* __restrict__ Vbt,
                                                  u16* __restrict__ attn, int T) {
    __shared__ u16 Ks[2][64 * 128];
    __shared__ u16 Vt[2][128 * 64];
    __shared__ u16 Ps[64 * 64];
    int tid = threadIdx.x;
    int lane = tid & 63, wave = tid >> 6;
    int quad = lane >> 4, l15 = lane & 15;
    int swb8 = (l15 & 7) * 8;  // row-XOR term: (s^x)*8 == s*8 ^ x*8
    int h = blockIdx.y;
    int j = (int)blockIdx.x;   // 0..31
    int kvh = h >> 1;

    const u16* kbase = Kb + (size_t)kvh * T * 128;
    const u16* vbase = Vbt + (size_t)kvh * 128 * T;

    int krow_ = (lane >> 4);
    int kseg_ = (lane & 15);
    int vrow_ = (lane >> 3);
    int vseg_ = (lane & 7);

    auto stage = [&](int s0, int b) {
        #pragma unroll
        for (int i = 0; i < 4; i++) {
            int ch = wave * 4 + i;
            int r = ch * 4 + krow_;
            int s = kseg_ ^ (r & 7);
            gload_lds16(kbase + (size_t)(s0 + r) * 128 + s * 8, &Ks[b][ch * 512]);
        }
        #pragma unroll
        for (int i = 0; i < 4; i++) {
            int ch = wave * 4 + i;
            int d = ch * 8 + vrow_;
            int s = vseg_ ^ (d & 7);
            gload_lds16(vbase + (size_t)d * T + s0 + s * 8, &Vt[b][ch * 512]);
        }
    };

    bf16x8 onesf;
    #pragma unroll
    for (int i = 0; i < 8; i++) onesf[i] = (__bf16)1.0f;
    f32x4 zero = {0.f, 0.f, 0.f, 0.f};
    const float L2E = 1.44269504f;

    for (int pass = 0; pass < 2; ++pass) {
        int qt = pass == 0 ? (63 - j) : j;
        int q0 = qt * 64;

        bf16x8 qf[4];
        {
            const u16* qp = Qb + ((size_t)h * T + q0 + 16 * wave + l15) * 128 + quad * 8;
            #pragma unroll
            for (int kk = 0; kk < 4; kk++) qf[kk] = ld_frag(qp + kk * 32);
        }

        float m_i = -3.0e38f;       // per-lane: q-row = 16*wave + l15
        f32x4 lsum = zero;          // C-layout rows: q = 16*wave + quad*4 + r
        f32x4 o[8];
        for (int dt = 0; dt < 8; dt++) o[dt] = zero;

        int ntiles = qt + 1;
        stage(0, 0);
        __syncthreads();  // vmcnt(0): tile 0 resident

        for (int it = 0; it < ntiles; ++it) {
            int b = it & 1;
            if (it + 1 < ntiles) stage((it + 1) * 64, 1 - b);  // async into other buffer
            int s0 = it * 64;

            // S^T: A=K (m->s), B=Q (n->q). scT[jt][r]: s = jt*16+quad*4+r, q = 16*wave+l15
            f32x4 scT[4];
            for (int jt = 0; jt < 4; jt++) scT[jt] = zero;
            #pragma unroll
            for (int kk = 0; kk < 4; kk++)
                #pragma unroll
                for (int jt = 0; jt < 4; jt++) {
                    bf16x8 kfrag = ld_frag(&Ks[b][(jt * 16 + l15) * 128 + ((kk * 32 + quad * 8) ^ swb8)]);
                    scT[jt] = __builtin_amdgcn_mfma_f32_16x16x32_bf16(kfrag, qf[kk], scT[jt], 0, 0, 0);
                }

            if (s0 == q0) {  // diagonal tile: mask s > q
                int qloc = 16 * wave + l15;
                #pragma unroll
                for (int jt = 0; jt < 4; jt++)
                    for (int r = 0; r < 4; r++)
                        if (jt * 16 + quad * 4 + r > qloc) scT[jt][r] = -1e30f;
            }

            // lane-local max over 16 scores (same q), then 2-step butterfly
            float mt = scT[0][0];
            #pragma unroll
            for (int jt = 0; jt < 4; jt++)
                for (int r = 0; r < 4; r++) mt = fmaxf(mt, scT[jt][r]);
            mt = fmaxf(mt, __shfl_xor(mt, 16));
            mt = fmaxf(mt, __shfl_xor(mt, 32));
            float mnew = fmaxf(m_i, mt);
            float alpha = __expf(m_i - mnew);
            m_i = mnew;
            float mls = mnew * L2E;

            #pragma unroll
            for (int jt = 0; jt < 4; jt++)
                for (int r = 0; r < 4; r++)
                    scT[jt][r] = exp2f(fmaf(scT[jt][r], L2E, -mls));

            // P^T -> Ps[q][s]: 4 consecutive s per (jt) -> one packed b64 write
            {
                int prow = 16 * wave + l15;
                #pragma unroll
                for (int jt = 0; jt < 4; jt++) {
                    int s8 = 2 * jt + (quad >> 1);
                    uint2 wv;
                    wv.x = pack_bf16(scT[jt][1], scT[jt][0]);
                    wv.y = pack_bf16(scT[jt][3], scT[jt][2]);
                    *reinterpret_cast<uint2*>(&Ps[prow * 64 + (s8 ^ (l15 & 7)) * 8 + (quad & 1) * 4]) = wv;
                }
            }

            // alpha-skip: rescale only when some lane's max advanced (alpha != 1)
            if (__any(alpha != 1.0f)) {
                float av[4];
                #pragma unroll
                for (int r = 0; r < 4; r++) av[r] = __shfl(alpha, quad * 4 + r);
                #pragma unroll
                for (int r = 0; r < 4; r++) lsum[r] *= av[r];
                #pragma unroll
                for (int dt = 0; dt < 8; dt++)
                    for (int r = 0; r < 4; r++) o[dt][r] *= av[r];
            }

            asm volatile("s_waitcnt lgkmcnt(0)" ::: "memory");  // wave-private Ps ordering

            #pragma unroll
            for (int kk2 = 0; kk2 < 2; kk2++) {
                bf16x8 pa = ld_frag(&Ps[(16 * wave + l15) * 64 + (((4 * kk2 + quad) ^ (l15 & 7)) * 8)]);
                lsum = __builtin_amdgcn_mfma_f32_16x16x32_bf16(pa, onesf, lsum, 0, 0, 0);
                #pragma unroll
                for (int dt = 0; dt < 8; dt++) {
                    bf16x8 vb = ld_frag(&Vt[b][(dt * 16 + l15) * 64 + ((kk2 * 32 + quad * 8) ^ swb8)]);
                    o[dt] = __builtin_amdgcn_mfma_f32_16x16x32_bf16(pa, vb, o[dt], 0, 0, 0);
                }
            }
            __syncthreads();  // drains next-tile loads (post-compute) + buffer handoff
        }

        float inv[4];
        for (int r = 0; r < 4; r++) inv[r] = 1.f / lsum[r];
        for (int dt = 0; dt < 8; dt++)
            for (int r = 0; r < 4; r++) {
                int row = q0 + 16 * wave + quad * 4 + r;
                attn[(size_t)row * NQ + h * DHEAD + dt * 16 + l15] = f2bf(o[dt][r] * inv[r]);
            }
    }
}

extern "C" void kernel_launch(void* const* d_in, const int* in_sizes, int n_in,
                              void* d_out, int out_size, void* d_ws, size_t ws_size,
                              hipStream_t stream) {
    const float* x    = (const float*)d_in[0];
    const float* cosp = (const float*)d_in[1];
    const float* sinp = (const float*)d_in[2];
    const float* Wq   = (const float*)d_in[3];
    const float* Wk   = (const float*)d_in[4];
    const float* Wv   = (const float*)d_in[5];
    const float* Wo   = (const float*)d_in[6];
    const float* qnw  = (const float*)d_in[7];
    const float* knw  = (const float*)d_in[8];
    float* out = (float*)d_out;
    const int T = in_sizes[1] / 64;  // 4096

    char* ws = (char*)d_ws;
    size_t off = 0;
    auto alloc = [&](size_t bytes) {
        char* p = ws + off;
        off += (bytes + 255) & ~(size_t)255;
        return p;
    };
    u16*   xb     = (u16*)alloc((size_t)T * HID * 2);
    u16*   Wqkvb  = (u16*)alloc((size_t)4096 * HID * 2);  // rows: q 0..2047, k 2048..3071, v 3072..4095
    u16*   Wob    = (u16*)alloc((size_t)HID * NQ * 2);
    u16*   qkvb   = (u16*)alloc((size_t)T * 4096 * 2);    // bf16 intermediate
    u16*   Qb     = (u16*)alloc((size_t)H2 * T * DHEAD * 2);
    u16*   Kb     = (u16*)alloc((size_t)HKV * T * DHEAD * 2);
    u16*   Vbt    = (u16*)alloc((size_t)HKV * DHEAD * T * 2);
    u16*   attn   = (u16*)alloc((size_t)T * NQ * 2);

    cast_f32_bf16<<<(T * HID / 4 + 255) / 256, 256, 0, stream>>>(x, xb, T * HID / 4);
    transpose_cast_all<<<6144, 256, 0, stream>>>(Wq, Wk, Wv, Wo, Wqkvb, Wob);

    // fused QKV: C[T][4096] bf16
    gemm_bf16_t<true><<<dim3(4096 / 128, T / 128), 256, 0, stream>>>(xb, Wqkvb, qkvb, T, 4096, HID);

    const float scale = 0.08838834764831845f;  // 128^-0.5 folded into Q
    norm_rope_qk<<<T * 24 / 4, 256, 0, stream>>>(qkvb, cosp, sinp, qnw, knw, Qb, Kb, T, scale);
    v_transpose<<<dim3(T / 64, HKV), 256, 0, stream>>>(qkvb, Vbt, T);

    flash_attn<<<dim3(32, H2), 256, 0, stream>>>(Qb, Kb, Vbt, attn, T);

    gemm_bf16_n64<<<dim3(HID / 64, T / 128), 256, 0, stream>>>(attn, Wob, out, T, HID, NQ);
}